// Round 2
// baseline (230.185 us; speedup 1.0000x reference)
//
#include <hip/hip_runtime.h>

typedef _Float16 half8 __attribute__((ext_vector_type(8)));
typedef float f32x4 __attribute__((ext_vector_type(4)));
typedef unsigned short u16;

#define NHEAD 12
#define DHEAD 64
#define DM    768
#define TSEQ  1024

// ws layout (fp16 elements). ctx aliases xh (xh dead after qkv GEMM).
static constexpr size_t OFF_XH  = 0;         // [4096][768]
static constexpr size_t OFF_WQH = 3145728;   // [768][768]
static constexpr size_t OFF_WKH = 3735552;
static constexpr size_t OFF_WVH = 4325376;
static constexpr size_t OFF_WOH = 4915200;
static constexpr size_t OFF_Q   = 5505024;   // [48][1024][64]
static constexpr size_t OFF_K   = 8650752;   // [48][1024][64]
static constexpr size_t OFF_VT  = 11796480;  // [48][64][1024]
static constexpr size_t OFF_CTX = 0;         // [4096][768], aliases XH
// total: 14,942,208 fp16 = ~28.5 MiB of ws

// ---------------- fp32 -> fp16 conversion of x + 4 weights ----------------
__global__ void cvt_kernel(const float* __restrict__ x, const float* __restrict__ wq,
                           const float* __restrict__ wk, const float* __restrict__ wv,
                           const float* __restrict__ wo, _Float16* __restrict__ ws) {
    int seg = blockIdx.y;
    const float* src;
    _Float16* dst;
    int n;
    if (seg == 0)      { src = x;  dst = ws + OFF_XH;  n = 3145728; }
    else if (seg == 1) { src = wq; dst = ws + OFF_WQH; n = 589824; }
    else if (seg == 2) { src = wk; dst = ws + OFF_WKH; n = 589824; }
    else if (seg == 3) { src = wv; dst = ws + OFF_WVH; n = 589824; }
    else               { src = wo; dst = ws + OFF_WOH; n = 589824; }
    int i = (blockIdx.x * blockDim.x + threadIdx.x) * 8;
    if (i < n) {
        float4 v0 = *(const float4*)(src + i);
        float4 v1 = *(const float4*)(src + i + 4);
        half8 o;
        o[0] = (_Float16)v0.x; o[1] = (_Float16)v0.y;
        o[2] = (_Float16)v0.z; o[3] = (_Float16)v0.w;
        o[4] = (_Float16)v1.x; o[5] = (_Float16)v1.y;
        o[6] = (_Float16)v1.z; o[7] = (_Float16)v1.w;
        *(half8*)(dst + i) = o;
    }
}

// ---------------- QKV GEMM: C[m][n] = sum_k X[m][k] * W[n][k] ----------------
// block = 128 thr (2 waves), block tile 64(m) x 128(n), wave tile 64x64
// z selects {Wq->Q, Wk->K, Wv->V^T}
__global__ __launch_bounds__(128) void qkv_kernel(_Float16* __restrict__ ws) {
    const int z = blockIdx.z;
    const _Float16* __restrict__ xh = ws + OFF_XH;
    const _Float16* __restrict__ w  = ws + (z == 0 ? OFF_WQH : z == 1 ? OFF_WKH : OFF_WVH);
    _Float16* __restrict__ outp     = ws + (z == 0 ? OFF_Q   : z == 1 ? OFF_K   : OFF_VT);

    const int lane = threadIdx.x & 63;
    const int wid  = threadIdx.x >> 6;
    const int quad = lane >> 4, l15 = lane & 15;
    const int mb = blockIdx.x * 64;
    const int nb = blockIdx.y * 128 + wid * 64;

    const _Float16* ap = xh + (size_t)(mb + l15) * DM + quad * 8;
    const _Float16* bp = w  + (size_t)(nb + l15) * DM + quad * 8;

    f32x4 acc[4][4] = {};
    for (int k0 = 0; k0 < DM; k0 += 32) {
        half8 a[4], b[4];
#pragma unroll
        for (int t = 0; t < 4; t++) {
            a[t] = *(const half8*)(ap + (size_t)t * 16 * DM + k0);
            b[t] = *(const half8*)(bp + (size_t)t * 16 * DM + k0);
        }
#pragma unroll
        for (int mt = 0; mt < 4; mt++)
#pragma unroll
            for (int nt = 0; nt < 4; nt++)
                acc[mt][nt] = __builtin_amdgcn_mfma_f32_16x16x32_f16(a[mt], b[nt], acc[mt][nt], 0, 0, 0);
    }

#pragma unroll
    for (int mt = 0; mt < 4; mt++)
#pragma unroll
        for (int nt = 0; nt < 4; nt++)
#pragma unroll
            for (int r = 0; r < 4; r++) {
                int m = mb + mt * 16 + quad * 4 + r;   // token row
                int n = nb + nt * 16 + l15;            // out feature
                int bb = m >> 10, tt = m & 1023;
                int h = n >> 6, d = n & 63;
                size_t idx = (z < 2)
                    ? ((size_t)(bb * NHEAD + h) * TSEQ + tt) * DHEAD + d   // [bh][t][d]
                    : ((size_t)(bb * NHEAD + h) * DHEAD + d) * TSEQ + tt;  // [bh][d][t]
                outp[idx] = (_Float16)acc[mt][nt][r];
            }
}

// ---------------- flash attention ----------------
// grid (8, 48); block 256 thr = 4 waves; wave = 32 q-rows; key tiles of 64
__global__ __launch_bounds__(256) void attn_kernel(_Float16* __restrict__ ws) {
    __shared__ __align__(16) _Float16 ldsP[4][32 * 72];  // per-wave P tile, row stride 72

    const int lane = threadIdx.x & 63;
    const int wid  = threadIdx.x >> 6;
    const int quad = lane >> 4, l15 = lane & 15;
    const int bh = blockIdx.y;
    const int q0 = blockIdx.x * 128 + wid * 32;

    const _Float16* __restrict__ Q  = ws + OFF_Q  + (size_t)bh * TSEQ * DHEAD;
    const _Float16* __restrict__ K  = ws + OFF_K  + (size_t)bh * TSEQ * DHEAD;
    const _Float16* __restrict__ VT = ws + OFF_VT + (size_t)bh * DHEAD * TSEQ;
    _Float16* __restrict__ ctx = ws + OFF_CTX;
    _Float16* pbase = ldsP[wid];

    // preload Q fragments: qf[mt][ks]
    half8 qf[2][2];
#pragma unroll
    for (int mt = 0; mt < 2; mt++)
#pragma unroll
        for (int ks = 0; ks < 2; ks++)
            qf[mt][ks] = *(const half8*)(Q + (size_t)(q0 + mt * 16 + l15) * DHEAD + ks * 32 + quad * 8);

    float mrun[2][4], lrun[2][4];
    f32x4 oacc[2][4] = {};
#pragma unroll
    for (int mt = 0; mt < 2; mt++)
#pragma unroll
        for (int r = 0; r < 4; r++) { mrun[mt][r] = -1e30f; lrun[mt][r] = 0.f; }

    for (int kt = 0; kt < TSEQ; kt += 64) {
        // K fragments: kf[n][ks]
        half8 kf[4][2];
#pragma unroll
        for (int n = 0; n < 4; n++)
#pragma unroll
            for (int ks = 0; ks < 2; ks++)
                kf[n][ks] = *(const half8*)(K + (size_t)(kt + n * 16 + l15) * DHEAD + ks * 32 + quad * 8);

        // S = Q K^T (C layout)
        f32x4 s[2][4] = {};
#pragma unroll
        for (int mt = 0; mt < 2; mt++)
#pragma unroll
            for (int n = 0; n < 4; n++)
#pragma unroll
                for (int ks = 0; ks < 2; ks++)
                    s[mt][n] = __builtin_amdgcn_mfma_f32_16x16x32_f16(qf[mt][ks], kf[n][ks], s[mt][n], 0, 0, 0);

#pragma unroll
        for (int mt = 0; mt < 2; mt++)
#pragma unroll
            for (int n = 0; n < 4; n++)
                s[mt][n] *= 0.125f;  // 1/sqrt(64)

        // online softmax per q-row (row = quad*4 + r within 16-group)
#pragma unroll
        for (int mt = 0; mt < 2; mt++) {
#pragma unroll
            for (int r = 0; r < 4; r++) {
                float tm = fmaxf(fmaxf(s[mt][0][r], s[mt][1][r]), fmaxf(s[mt][2][r], s[mt][3][r]));
#pragma unroll
                for (int off = 1; off < 16; off <<= 1) tm = fmaxf(tm, __shfl_xor(tm, off, 64));
                float mnew = fmaxf(mrun[mt][r], tm);
                float alpha = __expf(mrun[mt][r] - mnew);
                mrun[mt][r] = mnew;
                float ts = 0.f;
#pragma unroll
                for (int n = 0; n < 4; n++) {
                    float e = __expf(s[mt][n][r] - mnew);
                    s[mt][n][r] = e;  // reuse s as P
                    ts += e;
                }
#pragma unroll
                for (int off = 1; off < 16; off <<= 1) ts += __shfl_xor(ts, off, 64);
                lrun[mt][r] = lrun[mt][r] * alpha + ts;
#pragma unroll
                for (int dn = 0; dn < 4; dn++) oacc[mt][dn][r] *= alpha;
            }
        }

        // P: C layout -> LDS (fp16), rows 32, stride 72
#pragma unroll
        for (int mt = 0; mt < 2; mt++)
#pragma unroll
            for (int n = 0; n < 4; n++)
#pragma unroll
                for (int r = 0; r < 4; r++)
                    pbase[(mt * 16 + quad * 4 + r) * 72 + n * 16 + l15] = (_Float16)s[mt][n][r];

        // V^T fragments: vf[dn][ks] (rows d, contiguous keys)
        half8 vf[4][2];
#pragma unroll
        for (int dn = 0; dn < 4; dn++)
#pragma unroll
            for (int ks = 0; ks < 2; ks++)
                vf[dn][ks] = *(const half8*)(VT + (size_t)(dn * 16 + l15) * TSEQ + kt + ks * 32 + quad * 8);

        // P back from LDS in A layout: pf[mt][ks]
        half8 pf[2][2];
#pragma unroll
        for (int mt = 0; mt < 2; mt++)
#pragma unroll
            for (int ks = 0; ks < 2; ks++)
                pf[mt][ks] = *(const half8*)(pbase + (size_t)(mt * 16 + l15) * 72 + ks * 32 + quad * 8);

        // O += P V
#pragma unroll
        for (int mt = 0; mt < 2; mt++)
#pragma unroll
            for (int dn = 0; dn < 4; dn++)
#pragma unroll
                for (int ks = 0; ks < 2; ks++)
                    oacc[mt][dn] = __builtin_amdgcn_mfma_f32_16x16x32_f16(pf[mt][ks], vf[dn][ks], oacc[mt][dn], 0, 0, 0);
    }

    // epilogue: O / l -> ctx[b][t][h*64+d] (fp16)
    const int b_ = bh / NHEAD, h = bh % NHEAD;
#pragma unroll
    for (int mt = 0; mt < 2; mt++)
#pragma unroll
        for (int dn = 0; dn < 4; dn++)
#pragma unroll
            for (int r = 0; r < 4; r++) {
                int t_ = q0 + mt * 16 + quad * 4 + r;
                int col = h * DHEAD + dn * 16 + l15;
                float v = oacc[mt][dn][r] / lrun[mt][r];
                ctx[((size_t)(b_ * TSEQ + t_)) * DM + col] = (_Float16)v;
            }
}

// ---------------- output projection: out = ctx @ Wo^T + bo (fp32 out) ----------------
__global__ __launch_bounds__(128) void proj_kernel(const _Float16* __restrict__ ws,
                                                   const float* __restrict__ bo,
                                                   float* __restrict__ out) {
    const _Float16* __restrict__ ctx = ws + OFF_CTX;
    const _Float16* __restrict__ w   = ws + OFF_WOH;

    const int lane = threadIdx.x & 63;
    const int wid  = threadIdx.x >> 6;
    const int quad = lane >> 4, l15 = lane & 15;
    const int mb = blockIdx.x * 64;
    const int nb = blockIdx.y * 128 + wid * 64;

    const _Float16* ap = ctx + (size_t)(mb + l15) * DM + quad * 8;
    const _Float16* bp = w   + (size_t)(nb + l15) * DM + quad * 8;

    f32x4 acc[4][4] = {};
    for (int k0 = 0; k0 < DM; k0 += 32) {
        half8 a[4], b[4];
#pragma unroll
        for (int t = 0; t < 4; t++) {
            a[t] = *(const half8*)(ap + (size_t)t * 16 * DM + k0);
            b[t] = *(const half8*)(bp + (size_t)t * 16 * DM + k0);
        }
#pragma unroll
        for (int mt = 0; mt < 4; mt++)
#pragma unroll
            for (int nt = 0; nt < 4; nt++)
                acc[mt][nt] = __builtin_amdgcn_mfma_f32_16x16x32_f16(a[mt], b[nt], acc[mt][nt], 0, 0, 0);
    }

#pragma unroll
    for (int mt = 0; mt < 4; mt++)
#pragma unroll
        for (int nt = 0; nt < 4; nt++)
#pragma unroll
            for (int r = 0; r < 4; r++) {
                int m = mb + mt * 16 + quad * 4 + r;
                int n = nb + nt * 16 + l15;
                out[(size_t)m * DM + n] = acc[mt][nt][r] + bo[n];
            }
}

extern "C" void kernel_launch(void* const* d_in, const int* in_sizes, int n_in,
                              void* d_out, int out_size, void* d_ws, size_t ws_size,
                              hipStream_t stream) {
    const float* x  = (const float*)d_in[0];
    const float* wq = (const float*)d_in[1];
    const float* wk = (const float*)d_in[2];
    const float* wv = (const float*)d_in[3];
    const float* wo = (const float*)d_in[4];
    const float* bo = (const float*)d_in[5];
    _Float16* ws = (_Float16*)d_ws;
    float* out = (float*)d_out;

    cvt_kernel<<<dim3(1536, 5, 1), 256, 0, stream>>>(x, wq, wk, wv, wo, ws);
    qkv_kernel<<<dim3(64, 6, 3), 128, 0, stream>>>(ws);
    attn_kernel<<<dim3(8, 48, 1), 256, 0, stream>>>(ws);
    proj_kernel<<<dim3(64, 6, 1), 128, 0, stream>>>(ws, bo, out);
}

// Round 3
// 204.803 us; speedup vs baseline: 1.1239x; 1.1239x over previous
//
#include <hip/hip_runtime.h>

typedef _Float16 half8 __attribute__((ext_vector_type(8)));
typedef float f32x4 __attribute__((ext_vector_type(4)));
typedef unsigned short u16;

#define NHEAD 12
#define DHEAD 64
#define DM    768
#define TSEQ  1024

// ws layout (fp16 elements). ctx aliases xh (xh dead after qkv GEMM).
static constexpr size_t OFF_XH  = 0;         // [4096][768]
static constexpr size_t OFF_WQH = 3145728;   // [768][768]
static constexpr size_t OFF_WKH = 3735552;
static constexpr size_t OFF_WVH = 4325376;
static constexpr size_t OFF_WOH = 4915200;
static constexpr size_t OFF_Q   = 5505024;   // [48][1024][64]
static constexpr size_t OFF_K   = 8650752;   // [48][1024][64]
static constexpr size_t OFF_VT  = 11796480;  // [48][64][1024]
static constexpr size_t OFF_CTX = 0;         // [4096][768], aliases XH

// ---------------- fp32 -> fp16 conversion of x + 4 weights ----------------
__global__ void cvt_kernel(const float* __restrict__ x, const float* __restrict__ wq,
                           const float* __restrict__ wk, const float* __restrict__ wv,
                           const float* __restrict__ wo, _Float16* __restrict__ ws) {
    int seg = blockIdx.y;
    const float* src;
    _Float16* dst;
    int n;
    if (seg == 0)      { src = x;  dst = ws + OFF_XH;  n = 3145728; }
    else if (seg == 1) { src = wq; dst = ws + OFF_WQH; n = 589824; }
    else if (seg == 2) { src = wk; dst = ws + OFF_WKH; n = 589824; }
    else if (seg == 3) { src = wv; dst = ws + OFF_WVH; n = 589824; }
    else               { src = wo; dst = ws + OFF_WOH; n = 589824; }
    int i = (blockIdx.x * blockDim.x + threadIdx.x) * 8;
    if (i < n) {
        float4 v0 = *(const float4*)(src + i);
        float4 v1 = *(const float4*)(src + i + 4);
        half8 o;
        o[0] = (_Float16)v0.x; o[1] = (_Float16)v0.y;
        o[2] = (_Float16)v0.z; o[3] = (_Float16)v0.w;
        o[4] = (_Float16)v1.x; o[5] = (_Float16)v1.y;
        o[6] = (_Float16)v1.z; o[7] = (_Float16)v1.w;
        *(half8*)(dst + i) = o;
    }
}

// ---------------- QKV GEMM ----------------
// z=0: Q = X Wq^T -> [bh][t][d];  z=1: K -> [bh][t][d]
// z=2: V^T = Wv X^T -> [bh][d][t]  (A/B roles swapped so stores are coalesced)
__global__ __launch_bounds__(128) void qkv_kernel(_Float16* __restrict__ ws) {
    const int z = blockIdx.z;
    const _Float16* __restrict__ xh = ws + OFF_XH;
    const _Float16* __restrict__ w  = ws + (z == 0 ? OFF_WQH : z == 1 ? OFF_WKH : OFF_WVH);
    _Float16* __restrict__ outp     = ws + (z == 0 ? OFF_Q   : z == 1 ? OFF_K   : OFF_VT);

    const int lane = threadIdx.x & 63;
    const int wid  = threadIdx.x >> 6;
    const int quad = lane >> 4, l15 = lane & 15;

    int mb, nb;
    const _Float16 *ap, *bp;
    if (z < 2) {
        mb = blockIdx.x * 64;                  // tokens
        nb = blockIdx.y * 128 + wid * 64;      // features
        ap = xh + (size_t)(mb + l15) * DM + quad * 8;
        bp = w  + (size_t)(nb + l15) * DM + quad * 8;
    } else {
        int flat = blockIdx.x * 6 + blockIdx.y;  // 384 blocks -> 12 x 32
        mb = (flat % 12) * 64;                   // features
        nb = (flat / 12) * 128 + wid * 64;       // tokens
        ap = w  + (size_t)(mb + l15) * DM + quad * 8;
        bp = xh + (size_t)(nb + l15) * DM + quad * 8;
    }

    f32x4 acc[4][4] = {};
    for (int k0 = 0; k0 < DM; k0 += 32) {
        half8 a[4], b[4];
#pragma unroll
        for (int t = 0; t < 4; t++) {
            a[t] = *(const half8*)(ap + (size_t)t * 16 * DM + k0);
            b[t] = *(const half8*)(bp + (size_t)t * 16 * DM + k0);
        }
#pragma unroll
        for (int mt = 0; mt < 4; mt++)
#pragma unroll
            for (int nt = 0; nt < 4; nt++)
                acc[mt][nt] = __builtin_amdgcn_mfma_f32_16x16x32_f16(a[mt], b[nt], acc[mt][nt], 0, 0, 0);
    }

#pragma unroll
    for (int mt = 0; mt < 4; mt++)
#pragma unroll
        for (int nt = 0; nt < 4; nt++)
#pragma unroll
            for (int r = 0; r < 4; r++) {
                int m = mb + mt * 16 + quad * 4 + r;
                int n = nb + nt * 16 + l15;
                size_t idx;
                if (z < 2) {
                    int bb = m >> 10, tt = m & 1023;
                    int h = n >> 6, d = n & 63;
                    idx = ((size_t)(bb * NHEAD + h) * TSEQ + tt) * DHEAD + d;  // [bh][t][d]
                } else {
                    int h = m >> 6, d = m & 63;
                    int bb = n >> 10, tt = n & 1023;
                    idx = ((size_t)(bb * NHEAD + h) * DHEAD + d) * TSEQ + tt;  // [bh][d][t]
                }
                outp[idx] = (_Float16)acc[mt][nt][r];
            }
}

// ---------------- flash attention ----------------
// grid (16, 48); block 256 = 4 waves; block q-tile 64, wave q-tile 16; key tiles of 64
// K/VT staged in LDS (XOR-swizzled 16B chunks), shared by all 4 waves; reg prefetch.
__global__ __launch_bounds__(256, 3) void attn_kernel(_Float16* __restrict__ ws) {
    __shared__ __align__(16) _Float16 ldsK[64 * 64];
    __shared__ __align__(16) _Float16 ldsV[64 * 64];
    __shared__ __align__(16) _Float16 ldsP[4][16 * 72];

    const int tid  = threadIdx.x;
    const int lane = tid & 63;
    const int wid  = tid >> 6;
    const int quad = lane >> 4, l15 = lane & 15;
    const int bh = blockIdx.y;
    const int q0 = blockIdx.x * 64 + wid * 16;

    const _Float16* __restrict__ Q  = ws + OFF_Q  + (size_t)bh * TSEQ * DHEAD;
    const _Float16* __restrict__ K  = ws + OFF_K  + (size_t)bh * TSEQ * DHEAD;
    const _Float16* __restrict__ VT = ws + OFF_VT + (size_t)bh * DHEAD * TSEQ;
    _Float16* __restrict__ ctx = ws + OFF_CTX;
    _Float16* pbase = ldsP[wid];

    // staging geometry: 64x64 fp16 tile = 512 x 16B chunks; thread t handles
    // chunks t and t+256. row = chunk>>3, c = chunk&7, phys chunk = c ^ (row&7).
    const int srow0 = tid >> 3, sc0 = tid & 7;
    const int ldsOff0 = srow0 * 64 + ((sc0 ^ (srow0 & 7)) * 8);
    const int ldsOff1 = (srow0 + 32) * 64 + ((sc0 ^ (srow0 & 7)) * 8);  // (srow0+32)&7==srow0&7

    // preload Q fragments (A layout: row=l15, k=ks*32+quad*8)
    half8 qf[2];
#pragma unroll
    for (int ks = 0; ks < 2; ks++)
        qf[ks] = *(const half8*)(Q + (size_t)(q0 + l15) * DHEAD + ks * 32 + quad * 8);

    float mrun[4], lrun[4];
    f32x4 oacc[4] = {};
#pragma unroll
    for (int r = 0; r < 4; r++) { mrun[r] = -1e30f; lrun[r] = 0.f; }

    // prefetch tile 0 into regs
    uint4 ka, kb, va, vb;
    ka = *(const uint4*)(K + tid * 8);
    kb = *(const uint4*)(K + 2048 + tid * 8);
    va = *(const uint4*)(VT + (size_t)srow0 * TSEQ + sc0 * 8);
    vb = *(const uint4*)(VT + (size_t)(srow0 + 32) * TSEQ + sc0 * 8);

    for (int kt = 0; kt < TSEQ; kt += 64) {
        // stage current tile
        *(uint4*)(ldsK + ldsOff0) = ka;
        *(uint4*)(ldsK + ldsOff1) = kb;
        *(uint4*)(ldsV + ldsOff0) = va;
        *(uint4*)(ldsV + ldsOff1) = vb;
        __syncthreads();

        // prefetch next tile
        if (kt + 64 < TSEQ) {
            ka = *(const uint4*)(K + (kt + 64) * DHEAD + tid * 8);
            kb = *(const uint4*)(K + (kt + 64) * DHEAD + 2048 + tid * 8);
            va = *(const uint4*)(VT + (size_t)srow0 * TSEQ + kt + 64 + sc0 * 8);
            vb = *(const uint4*)(VT + (size_t)(srow0 + 32) * TSEQ + kt + 64 + sc0 * 8);
        }

        // K fragments from LDS (B layout: row=key=n*16+l15, k=ks*32+quad*8)
        half8 kf[4][2];
#pragma unroll
        for (int n = 0; n < 4; n++)
#pragma unroll
            for (int ks = 0; ks < 2; ks++) {
                int row = n * 16 + l15;
                int phys = (ks * 4 + quad) ^ (row & 7);
                kf[n][ks] = *(const half8*)(ldsK + row * 64 + phys * 8);
            }

        // S = Q K^T (C layout)
        f32x4 s[4] = {};
#pragma unroll
        for (int n = 0; n < 4; n++)
#pragma unroll
            for (int ks = 0; ks < 2; ks++)
                s[n] = __builtin_amdgcn_mfma_f32_16x16x32_f16(qf[ks], kf[n][ks], s[n], 0, 0, 0);
#pragma unroll
        for (int n = 0; n < 4; n++) s[n] *= 0.125f;  // 1/sqrt(64)

        // online softmax, rows = quad*4 + r
#pragma unroll
        for (int r = 0; r < 4; r++) {
            float tm = fmaxf(fmaxf(s[0][r], s[1][r]), fmaxf(s[2][r], s[3][r]));
#pragma unroll
            for (int off = 1; off < 16; off <<= 1) tm = fmaxf(tm, __shfl_xor(tm, off, 64));
            float mnew = fmaxf(mrun[r], tm);
            float alpha = __expf(mrun[r] - mnew);
            mrun[r] = mnew;
            float ts = 0.f;
#pragma unroll
            for (int n = 0; n < 4; n++) {
                float e = __expf(s[n][r] - mnew);
                s[n][r] = e;
                ts += e;
            }
#pragma unroll
            for (int off = 1; off < 16; off <<= 1) ts += __shfl_xor(ts, off, 64);
            lrun[r] = lrun[r] * alpha + ts;
#pragma unroll
            for (int dn = 0; dn < 4; dn++) oacc[dn][r] *= alpha;
        }

        // P: C layout -> per-wave LDS (16 rows, stride 72)
#pragma unroll
        for (int n = 0; n < 4; n++)
#pragma unroll
            for (int r = 0; r < 4; r++)
                pbase[(quad * 4 + r) * 72 + n * 16 + l15] = (_Float16)s[n][r];

        // V^T fragments from LDS (B layout: row=d=dn*16+l15, k=key)
        half8 vf[4][2];
#pragma unroll
        for (int dn = 0; dn < 4; dn++)
#pragma unroll
            for (int ks = 0; ks < 2; ks++) {
                int row = dn * 16 + l15;
                int phys = (ks * 4 + quad) ^ (row & 7);
                vf[dn][ks] = *(const half8*)(ldsV + row * 64 + phys * 8);
            }

        // P in A layout
        half8 pf[2];
#pragma unroll
        for (int ks = 0; ks < 2; ks++)
            pf[ks] = *(const half8*)(pbase + l15 * 72 + ks * 32 + quad * 8);

        // O += P V
#pragma unroll
        for (int dn = 0; dn < 4; dn++)
#pragma unroll
            for (int ks = 0; ks < 2; ks++)
                oacc[dn] = __builtin_amdgcn_mfma_f32_16x16x32_f16(pf[ks], vf[dn][ks], oacc[dn], 0, 0, 0);

        __syncthreads();
    }

    // epilogue: O / l -> ctx[b][t][h*64+d] (fp16)
    const int b_ = bh / NHEAD, h = bh % NHEAD;
#pragma unroll
    for (int dn = 0; dn < 4; dn++)
#pragma unroll
        for (int r = 0; r < 4; r++) {
            int t_ = q0 + quad * 4 + r;
            int col = h * DHEAD + dn * 16 + l15;
            float v = oacc[dn][r] / lrun[r];
            ctx[((size_t)(b_ * TSEQ + t_)) * DM + col] = (_Float16)v;
        }
}

// ---------------- output projection: out = ctx @ Wo^T + bo (fp32 out) ----------------
__global__ __launch_bounds__(128) void proj_kernel(const _Float16* __restrict__ ws,
                                                   const float* __restrict__ bo,
                                                   float* __restrict__ out) {
    const _Float16* __restrict__ ctx = ws + OFF_CTX;
    const _Float16* __restrict__ w   = ws + OFF_WOH;

    const int lane = threadIdx.x & 63;
    const int wid  = threadIdx.x >> 6;
    const int quad = lane >> 4, l15 = lane & 15;
    const int mb = blockIdx.x * 64;
    const int nb = blockIdx.y * 128 + wid * 64;

    const _Float16* ap = ctx + (size_t)(mb + l15) * DM + quad * 8;
    const _Float16* bp = w   + (size_t)(nb + l15) * DM + quad * 8;

    f32x4 acc[4][4] = {};
    for (int k0 = 0; k0 < DM; k0 += 32) {
        half8 a[4], b[4];
#pragma unroll
        for (int t = 0; t < 4; t++) {
            a[t] = *(const half8*)(ap + (size_t)t * 16 * DM + k0);
            b[t] = *(const half8*)(bp + (size_t)t * 16 * DM + k0);
        }
#pragma unroll
        for (int mt = 0; mt < 4; mt++)
#pragma unroll
            for (int nt = 0; nt < 4; nt++)
                acc[mt][nt] = __builtin_amdgcn_mfma_f32_16x16x32_f16(a[mt], b[nt], acc[mt][nt], 0, 0, 0);
    }

#pragma unroll
    for (int mt = 0; mt < 4; mt++)
#pragma unroll
        for (int nt = 0; nt < 4; nt++)
#pragma unroll
            for (int r = 0; r < 4; r++) {
                int m = mb + mt * 16 + quad * 4 + r;
                int n = nb + nt * 16 + l15;
                out[(size_t)m * DM + n] = acc[mt][nt][r] + bo[n];
            }
}

extern "C" void kernel_launch(void* const* d_in, const int* in_sizes, int n_in,
                              void* d_out, int out_size, void* d_ws, size_t ws_size,
                              hipStream_t stream) {
    const float* x  = (const float*)d_in[0];
    const float* wq = (const float*)d_in[1];
    const float* wk = (const float*)d_in[2];
    const float* wv = (const float*)d_in[3];
    const float* wo = (const float*)d_in[4];
    const float* bo = (const float*)d_in[5];
    _Float16* ws = (_Float16*)d_ws;
    float* out = (float*)d_out;

    cvt_kernel<<<dim3(1536, 5, 1), 256, 0, stream>>>(x, wq, wk, wv, wo, ws);
    qkv_kernel<<<dim3(64, 6, 3), 128, 0, stream>>>(ws);
    attn_kernel<<<dim3(16, 48, 1), 256, 0, stream>>>(ws);
    proj_kernel<<<dim3(64, 6, 1), 128, 0, stream>>>(ws, bo, out);
}

// Round 4
// 160.839 us; speedup vs baseline: 1.4312x; 1.2733x over previous
//
#include <hip/hip_runtime.h>

typedef _Float16 half8 __attribute__((ext_vector_type(8)));
typedef float f32x4 __attribute__((ext_vector_type(4)));
typedef unsigned short u16;

#define NHEAD 12
#define DHEAD 64
#define DM    768
#define TSEQ  1024

// ws layout (fp16 elements). ctx aliases xh (xh dead after qkv GEMM).
static constexpr size_t OFF_XH  = 0;         // [4096][768]
static constexpr size_t OFF_WQH = 3145728;   // [768][768]
static constexpr size_t OFF_WKH = 3735552;
static constexpr size_t OFF_WVH = 4325376;
static constexpr size_t OFF_WOH = 4915200;
static constexpr size_t OFF_Q   = 5505024;   // [48][1024][64]
static constexpr size_t OFF_K   = 8650752;   // [48][1024][64]
static constexpr size_t OFF_VT  = 11796480;  // [48][64][1024]
static constexpr size_t OFF_CTX = 0;         // [4096][768], aliases XH

typedef const __attribute__((address_space(1))) void* gas_ptr;
typedef __attribute__((address_space(3))) void* las_ptr;
__device__ __forceinline__ void gload16(const _Float16* g, _Float16* l) {
    __builtin_amdgcn_global_load_lds((gas_ptr)g, (las_ptr)l, 16, 0, 0);
}

// ---------------- fp32 -> fp16 conversion of x + 4 weights ----------------
__global__ void cvt_kernel(const float* __restrict__ x, const float* __restrict__ wq,
                           const float* __restrict__ wk, const float* __restrict__ wv,
                           const float* __restrict__ wo, _Float16* __restrict__ ws) {
    int seg = blockIdx.y;
    const float* src;
    _Float16* dst;
    int n;
    if (seg == 0)      { src = x;  dst = ws + OFF_XH;  n = 3145728; }
    else if (seg == 1) { src = wq; dst = ws + OFF_WQH; n = 589824; }
    else if (seg == 2) { src = wk; dst = ws + OFF_WKH; n = 589824; }
    else if (seg == 3) { src = wv; dst = ws + OFF_WVH; n = 589824; }
    else               { src = wo; dst = ws + OFF_WOH; n = 589824; }
    int i = (blockIdx.x * blockDim.x + threadIdx.x) * 8;
    if (i < n) {
        float4 v0 = *(const float4*)(src + i);
        float4 v1 = *(const float4*)(src + i + 4);
        half8 o;
        o[0] = (_Float16)v0.x; o[1] = (_Float16)v0.y;
        o[2] = (_Float16)v0.z; o[3] = (_Float16)v0.w;
        o[4] = (_Float16)v1.x; o[5] = (_Float16)v1.y;
        o[6] = (_Float16)v1.z; o[7] = (_Float16)v1.w;
        *(half8*)(dst + i) = o;
    }
}

// ---------------- QKV GEMM, m97-style LDS-staged ----------------
// block 256 thr = 4 waves; tile BM=128 BN=128 BK=32; wave tile 64x64.
// z=0: Q = X Wq^T -> [bh][t][d];  z=1: K;  z=2: V^T = Wv X^T -> [bh][d][t]
__global__ __launch_bounds__(256) void qkv_kernel(_Float16* __restrict__ ws) {
    __shared__ __align__(16) _Float16 ldsA[128 * 32];
    __shared__ __align__(16) _Float16 ldsB[128 * 32];

    const int z = blockIdx.z;
    const _Float16* __restrict__ xh = ws + OFF_XH;
    const _Float16* __restrict__ w  = ws + (z == 0 ? OFF_WQH : z == 1 ? OFF_WKH : OFF_WVH);
    _Float16* __restrict__ outp     = ws + (z == 0 ? OFF_Q   : z == 1 ? OFF_K   : OFF_VT);

    const int tid  = threadIdx.x;
    const int lane = tid & 63;
    const int wid  = tid >> 6;
    const int quad = lane >> 4, l15 = lane & 15;
    const int wm = (wid & 1) * 64, wn = (wid >> 1) * 64;

    // A rows = "m" (tokens for z<2, features for z=2); B rows = "n"
    int mb, nb;
    const _Float16 *gA, *gB;
    if (z < 2) {
        mb = blockIdx.x * 128;              // tokens
        nb = blockIdx.y * 128;              // features
        gA = xh + (size_t)mb * DM;
        gB = w  + (size_t)nb * DM;
    } else {
        mb = blockIdx.y * 128;              // features
        nb = blockIdx.x * 128;              // tokens
        gA = w  + (size_t)mb * DM;
        gB = xh + (size_t)nb * DM;
    }

    // staging: wave wid stages rows [wid*32, wid*32+32); instr j covers 16 rows.
    const int srow = (lane >> 2);           // 0..15
    const int scol = (lane & 3) * 8;        // halfs
    const size_t goff0 = (size_t)(wid * 32 + srow) * DM + scol;
    const size_t goff1 = (size_t)(wid * 32 + 16 + srow) * DM + scol;
    _Float16* lA0 = ldsA + wid * 1024;      // +lane*8 halfs implicit
    _Float16* lA1 = ldsA + wid * 1024 + 512;
    _Float16* lB0 = ldsB + wid * 1024;
    _Float16* lB1 = ldsB + wid * 1024 + 512;

    f32x4 acc[4][4] = {};
    for (int k0 = 0; k0 < DM; k0 += 32) {
        gload16(gA + goff0 + k0, lA0);
        gload16(gA + goff1 + k0, lA1);
        gload16(gB + goff0 + k0, lB0);
        gload16(gB + goff1 + k0, lB1);
        __syncthreads();   // drains vmcnt -> LDS tile ready

        half8 a[4], b[4];
#pragma unroll
        for (int t = 0; t < 4; t++) {
            a[t] = *(const half8*)(ldsA + (wm + t * 16 + l15) * 32 + quad * 8);
            b[t] = *(const half8*)(ldsB + (wn + t * 16 + l15) * 32 + quad * 8);
        }
#pragma unroll
        for (int mt = 0; mt < 4; mt++)
#pragma unroll
            for (int nt = 0; nt < 4; nt++)
                acc[mt][nt] = __builtin_amdgcn_mfma_f32_16x16x32_f16(a[mt], b[nt], acc[mt][nt], 0, 0, 0);
        __syncthreads();   // all waves done reading before next stage
    }

#pragma unroll
    for (int mt = 0; mt < 4; mt++)
#pragma unroll
        for (int nt = 0; nt < 4; nt++)
#pragma unroll
            for (int r = 0; r < 4; r++) {
                int m = mb + wm + mt * 16 + quad * 4 + r;
                int n = nb + wn + nt * 16 + l15;
                size_t idx;
                if (z < 2) {
                    int bb = m >> 10, tt = m & 1023;
                    int h = n >> 6, d = n & 63;
                    idx = ((size_t)(bb * NHEAD + h) * TSEQ + tt) * DHEAD + d;  // [bh][t][d]
                } else {
                    int h = m >> 6, d = m & 63;
                    int bb = n >> 10, tt = n & 1023;
                    idx = ((size_t)(bb * NHEAD + h) * DHEAD + d) * TSEQ + tt;  // [bh][d][t]
                }
                outp[idx] = (_Float16)acc[mt][nt][r];
            }
}

// ---------------- flash attention ----------------
// grid (16, 48); block 256 = 4 waves; block q-tile 64, wave q-tile 16; key tiles of 64
// K/VT staged in LDS (XOR-swizzled 16B chunks), shared by all 4 waves; reg prefetch.
__global__ __launch_bounds__(256, 3) void attn_kernel(_Float16* __restrict__ ws) {
    __shared__ __align__(16) _Float16 ldsK[64 * 64];
    __shared__ __align__(16) _Float16 ldsV[64 * 64];
    __shared__ __align__(16) _Float16 ldsP[4][16 * 72];

    const int tid  = threadIdx.x;
    const int lane = tid & 63;
    const int wid  = tid >> 6;
    const int quad = lane >> 4, l15 = lane & 15;
    const int bh = blockIdx.y;
    const int q0 = blockIdx.x * 64 + wid * 16;

    const _Float16* __restrict__ Q  = ws + OFF_Q  + (size_t)bh * TSEQ * DHEAD;
    const _Float16* __restrict__ K  = ws + OFF_K  + (size_t)bh * TSEQ * DHEAD;
    const _Float16* __restrict__ VT = ws + OFF_VT + (size_t)bh * DHEAD * TSEQ;
    _Float16* __restrict__ ctx = ws + OFF_CTX;
    _Float16* pbase = ldsP[wid];

    const int srow0 = tid >> 3, sc0 = tid & 7;
    const int ldsOff0 = srow0 * 64 + ((sc0 ^ (srow0 & 7)) * 8);
    const int ldsOff1 = (srow0 + 32) * 64 + ((sc0 ^ (srow0 & 7)) * 8);

    half8 qf[2];
#pragma unroll
    for (int ks = 0; ks < 2; ks++)
        qf[ks] = *(const half8*)(Q + (size_t)(q0 + l15) * DHEAD + ks * 32 + quad * 8);

    float mrun[4], lrun[4];
    f32x4 oacc[4] = {};
#pragma unroll
    for (int r = 0; r < 4; r++) { mrun[r] = -1e30f; lrun[r] = 0.f; }

    uint4 ka, kb, va, vb;
    ka = *(const uint4*)(K + tid * 8);
    kb = *(const uint4*)(K + 2048 + tid * 8);
    va = *(const uint4*)(VT + (size_t)srow0 * TSEQ + sc0 * 8);
    vb = *(const uint4*)(VT + (size_t)(srow0 + 32) * TSEQ + sc0 * 8);

    for (int kt = 0; kt < TSEQ; kt += 64) {
        *(uint4*)(ldsK + ldsOff0) = ka;
        *(uint4*)(ldsK + ldsOff1) = kb;
        *(uint4*)(ldsV + ldsOff0) = va;
        *(uint4*)(ldsV + ldsOff1) = vb;
        __syncthreads();

        if (kt + 64 < TSEQ) {
            ka = *(const uint4*)(K + (kt + 64) * DHEAD + tid * 8);
            kb = *(const uint4*)(K + (kt + 64) * DHEAD + 2048 + tid * 8);
            va = *(const uint4*)(VT + (size_t)srow0 * TSEQ + kt + 64 + sc0 * 8);
            vb = *(const uint4*)(VT + (size_t)(srow0 + 32) * TSEQ + kt + 64 + sc0 * 8);
        }

        half8 kf[4][2];
#pragma unroll
        for (int n = 0; n < 4; n++)
#pragma unroll
            for (int ks = 0; ks < 2; ks++) {
                int row = n * 16 + l15;
                int phys = (ks * 4 + quad) ^ (row & 7);
                kf[n][ks] = *(const half8*)(ldsK + row * 64 + phys * 8);
            }

        f32x4 s[4] = {};
#pragma unroll
        for (int n = 0; n < 4; n++)
#pragma unroll
            for (int ks = 0; ks < 2; ks++)
                s[n] = __builtin_amdgcn_mfma_f32_16x16x32_f16(qf[ks], kf[n][ks], s[n], 0, 0, 0);
#pragma unroll
        for (int n = 0; n < 4; n++) s[n] *= 0.125f;

#pragma unroll
        for (int r = 0; r < 4; r++) {
            float tm = fmaxf(fmaxf(s[0][r], s[1][r]), fmaxf(s[2][r], s[3][r]));
#pragma unroll
            for (int off = 1; off < 16; off <<= 1) tm = fmaxf(tm, __shfl_xor(tm, off, 64));
            float mnew = fmaxf(mrun[r], tm);
            float alpha = __expf(mrun[r] - mnew);
            mrun[r] = mnew;
            float ts = 0.f;
#pragma unroll
            for (int n = 0; n < 4; n++) {
                float e = __expf(s[n][r] - mnew);
                s[n][r] = e;
                ts += e;
            }
#pragma unroll
            for (int off = 1; off < 16; off <<= 1) ts += __shfl_xor(ts, off, 64);
            lrun[r] = lrun[r] * alpha + ts;
#pragma unroll
            for (int dn = 0; dn < 4; dn++) oacc[dn][r] *= alpha;
        }

#pragma unroll
        for (int n = 0; n < 4; n++)
#pragma unroll
            for (int r = 0; r < 4; r++)
                pbase[(quad * 4 + r) * 72 + n * 16 + l15] = (_Float16)s[n][r];

        half8 vf[4][2];
#pragma unroll
        for (int dn = 0; dn < 4; dn++)
#pragma unroll
            for (int ks = 0; ks < 2; ks++) {
                int row = dn * 16 + l15;
                int phys = (ks * 4 + quad) ^ (row & 7);
                vf[dn][ks] = *(const half8*)(ldsV + row * 64 + phys * 8);
            }

        half8 pf[2];
#pragma unroll
        for (int ks = 0; ks < 2; ks++)
            pf[ks] = *(const half8*)(pbase + l15 * 72 + ks * 32 + quad * 8);

#pragma unroll
        for (int dn = 0; dn < 4; dn++)
#pragma unroll
            for (int ks = 0; ks < 2; ks++)
                oacc[dn] = __builtin_amdgcn_mfma_f32_16x16x32_f16(pf[ks], vf[dn][ks], oacc[dn], 0, 0, 0);

        __syncthreads();
    }

    const int b_ = bh / NHEAD, h = bh % NHEAD;
#pragma unroll
    for (int dn = 0; dn < 4; dn++)
#pragma unroll
        for (int r = 0; r < 4; r++) {
            int t_ = q0 + quad * 4 + r;
            int col = h * DHEAD + dn * 16 + l15;
            float v = oacc[dn][r] / lrun[r];
            ctx[((size_t)(b_ * TSEQ + t_)) * DM + col] = (_Float16)v;
        }
}

// ---------------- output projection, m97-style: out = ctx @ Wo^T + bo (fp32) ----------------
__global__ __launch_bounds__(256) void proj_kernel(const _Float16* __restrict__ ws,
                                                   const float* __restrict__ bo,
                                                   float* __restrict__ out) {
    __shared__ __align__(16) _Float16 ldsA[128 * 32];
    __shared__ __align__(16) _Float16 ldsB[128 * 32];

    const _Float16* __restrict__ gA = ws + OFF_CTX + (size_t)blockIdx.x * 128 * DM;
    const _Float16* __restrict__ gB = ws + OFF_WOH + (size_t)blockIdx.y * 128 * DM;

    const int tid  = threadIdx.x;
    const int lane = tid & 63;
    const int wid  = tid >> 6;
    const int quad = lane >> 4, l15 = lane & 15;
    const int wm = (wid & 1) * 64, wn = (wid >> 1) * 64;

    const int srow = (lane >> 2);
    const int scol = (lane & 3) * 8;
    const size_t goff0 = (size_t)(wid * 32 + srow) * DM + scol;
    const size_t goff1 = (size_t)(wid * 32 + 16 + srow) * DM + scol;
    _Float16* lA0 = ldsA + wid * 1024;
    _Float16* lA1 = ldsA + wid * 1024 + 512;
    _Float16* lB0 = ldsB + wid * 1024;
    _Float16* lB1 = ldsB + wid * 1024 + 512;

    f32x4 acc[4][4] = {};
    for (int k0 = 0; k0 < DM; k0 += 32) {
        gload16(gA + goff0 + k0, lA0);
        gload16(gA + goff1 + k0, lA1);
        gload16(gB + goff0 + k0, lB0);
        gload16(gB + goff1 + k0, lB1);
        __syncthreads();

        half8 a[4], b[4];
#pragma unroll
        for (int t = 0; t < 4; t++) {
            a[t] = *(const half8*)(ldsA + (wm + t * 16 + l15) * 32 + quad * 8);
            b[t] = *(const half8*)(ldsB + (wn + t * 16 + l15) * 32 + quad * 8);
        }
#pragma unroll
        for (int mt = 0; mt < 4; mt++)
#pragma unroll
            for (int nt = 0; nt < 4; nt++)
                acc[mt][nt] = __builtin_amdgcn_mfma_f32_16x16x32_f16(a[mt], b[nt], acc[mt][nt], 0, 0, 0);
        __syncthreads();
    }

    const int mb = blockIdx.x * 128, nb = blockIdx.y * 128;
#pragma unroll
    for (int mt = 0; mt < 4; mt++)
#pragma unroll
        for (int nt = 0; nt < 4; nt++)
#pragma unroll
            for (int r = 0; r < 4; r++) {
                int m = mb + wm + mt * 16 + quad * 4 + r;
                int n = nb + wn + nt * 16 + l15;
                out[(size_t)m * DM + n] = acc[mt][nt][r] + bo[n];
            }
}

extern "C" void kernel_launch(void* const* d_in, const int* in_sizes, int n_in,
                              void* d_out, int out_size, void* d_ws, size_t ws_size,
                              hipStream_t stream) {
    const float* x  = (const float*)d_in[0];
    const float* wq = (const float*)d_in[1];
    const float* wk = (const float*)d_in[2];
    const float* wv = (const float*)d_in[3];
    const float* wo = (const float*)d_in[4];
    const float* bo = (const float*)d_in[5];
    _Float16* ws = (_Float16*)d_ws;
    float* out = (float*)d_out;

    cvt_kernel<<<dim3(1536, 5, 1), 256, 0, stream>>>(x, wq, wk, wv, wo, ws);
    qkv_kernel<<<dim3(32, 6, 3), 256, 0, stream>>>(ws);
    attn_kernel<<<dim3(16, 48, 1), 256, 0, stream>>>(ws);
    proj_kernel<<<dim3(32, 6, 1), 256, 0, stream>>>(ws, bo, out);
}